// Round 1
// baseline (1067.715 us; speedup 1.0000x reference)
//
#include <hip/hip_runtime.h>

#define BATCH 8
#define NPTS 4096
#define NSAMP 512   // npoint = NPTS/8

// ---------------------------------------------------------------------------
// Kernel A: farthest point sampling. One block per batch, 256 threads.
// Each lane owns 16 points in registers; LDS holds a copy for broadcasts.
// Exact fp32 (no FMA) to match the numpy reference's selection bit-for-bit.
// ---------------------------------------------------------------------------
__global__ __launch_bounds__(256) void fps_kernel(const float* __restrict__ pcd,
                                                  float* __restrict__ new_xyz) {
  __shared__ float sx[NPTS], sy[NPTS], sz[NPTS];
  __shared__ float redv[4];
  __shared__ int   redi[4];
  __shared__ int   s_cur;

  const int b = blockIdx.x;
  const int t = threadIdx.x;
  const int lane = t & 63;
  const int wave = t >> 6;
  const float* xb = pcd + (size_t)b * NPTS * 3;

  float X[16], Y[16], Z[16], mind[16];
#pragma unroll
  for (int j = 0; j < 16; ++j) {
    int i = t + 256 * j;
    float x = xb[i * 3 + 0], y = xb[i * 3 + 1], z = xb[i * 3 + 2];
    X[j] = x; Y[j] = y; Z[j] = z;
    sx[i] = x; sy[i] = y; sz[i] = z;
    mind[j] = 10000000000.0f;
  }
  __syncthreads();

  int last = 0;
  for (int it = 0; it < NSAMP; ++it) {
    float px = sx[last], py = sy[last], pz = sz[last];
    if (t == 0) {
      size_t o = ((size_t)b * NSAMP + it) * 3;
      new_xyz[o + 0] = px; new_xyz[o + 1] = py; new_xyz[o + 2] = pz;
    }
    float bv = -1.0f; int bi = 0;
#pragma unroll
    for (int j = 0; j < 16; ++j) {
      float dx = __fsub_rn(X[j], px);
      float dy = __fsub_rn(Y[j], py);
      float dz = __fsub_rn(Z[j], pz);
      float d = __fadd_rn(__fadd_rn(__fmul_rn(dx, dx), __fmul_rn(dy, dy)),
                          __fmul_rn(dz, dz));
      float m = fminf(mind[j], d);
      mind[j] = m;
      if (m > bv) { bv = m; bi = t + 256 * j; }   // strict >: first occurrence
    }
    // wave argmax (prefer larger val; tie -> smaller index)
#pragma unroll
    for (int o = 32; o > 0; o >>= 1) {
      float ov = __shfl_down(bv, o);
      int   oi = __shfl_down(bi, o);
      if (ov > bv || (ov == bv && oi < bi)) { bv = ov; bi = oi; }
    }
    if (lane == 0) { redv[wave] = bv; redi[wave] = bi; }
    __syncthreads();
    if (t == 0) {
      float v = redv[0]; int i0 = redi[0];
#pragma unroll
      for (int w = 1; w < 4; ++w)
        if (redv[w] > v || (redv[w] == v && redi[w] < i0)) { v = redv[w]; i0 = redi[w]; }
      s_cur = i0;
    }
    __syncthreads();
    last = s_cur;
  }
}

// ---------------------------------------------------------------------------
// Tiled MLP layer: block = 16 n-threads x 16 oc-threads.
// h stored channel-major in LDS: h[c][n] with row stride NT.
// Weights read straight from global (L2-resident, lanes dedup/broadcast).
// FINAL: fuse bias+relu+max-over-n via LDS integer atomicMax (values >= 0).
// ---------------------------------------------------------------------------
template <int CIN, int COUT, int NT, bool FINAL>
__device__ __forceinline__ void layer(const float* __restrict__ w,
                                      const float* __restrict__ bias,
                                      const float* hin, float* hout, int tid) {
  constexpr int TN = NT / 16;
  constexpr int TOC = COUT / 16;
  const int tn = tid & 15, toc = tid >> 4;
  float acc[TOC][TN];
#pragma unroll
  for (int j = 0; j < TOC; ++j) {
    float bj = bias[toc * TOC + j];
#pragma unroll
    for (int i = 0; i < TN; ++i) acc[j][i] = bj;
  }
#pragma unroll 4
  for (int ic = 0; ic < CIN; ++ic) {
    float hv[TN];
#pragma unroll
    for (int i = 0; i < TN; ++i) hv[i] = hin[ic * NT + tn * TN + i];
    float wv[TOC];
#pragma unroll
    for (int j = 0; j < TOC; ++j) wv[j] = w[ic * COUT + toc * TOC + j];
#pragma unroll
    for (int j = 0; j < TOC; ++j)
#pragma unroll
      for (int i = 0; i < TN; ++i) acc[j][i] = fmaf(hv[i], wv[j], acc[j][i]);
  }
  if (FINAL) {
#pragma unroll
    for (int j = 0; j < TOC; ++j) {
      float m = 0.0f;  // relu floor
#pragma unroll
      for (int i = 0; i < TN; ++i) m = fmaxf(m, acc[j][i]);
      atomicMax((int*)&hout[toc * TOC + j], __float_as_int(m));
    }
  } else {
#pragma unroll
    for (int j = 0; j < TOC; ++j)
#pragma unroll
      for (int i = 0; i < TN; ++i)
        hout[(toc * TOC + j) * NT + tn * TN + i] = fmaxf(acc[j][i], 0.0f);
  }
}

// ---------------------------------------------------------------------------
// Kernel B: one block per (b, s) sample point. Ball query (3 scales, waves
// 0..2, ballot-prefix ordered append, exact fp32) then per-scale MLP + max,
// then fused final 320->1 linear.
// ---------------------------------------------------------------------------
__global__ __launch_bounds__(256) void msg_kernel(
    const float* __restrict__ pcd, const float* __restrict__ new_xyz,
    const float* __restrict__ w00, const float* __restrict__ b00,
    const float* __restrict__ w01, const float* __restrict__ b01,
    const float* __restrict__ w02, const float* __restrict__ b02,
    const float* __restrict__ w10, const float* __restrict__ b10,
    const float* __restrict__ w11, const float* __restrict__ b11,
    const float* __restrict__ w12, const float* __restrict__ b12,
    const float* __restrict__ w20, const float* __restrict__ b20,
    const float* __restrict__ w21, const float* __restrict__ b21,
    const float* __restrict__ w22, const float* __restrict__ b22,
    const float* __restrict__ wf, const float* __restrict__ bf,
    float* __restrict__ out) {
  __shared__ float hA[96 * 64];
  __shared__ float hB[64 * 64];
  __shared__ int   lists[176];   // 16 + 32 + 128
  __shared__ float feat[320];

  const int bs = blockIdx.x;
  const int b = bs >> 9;
  const int tid = threadIdx.x;
  const int lane = tid & 63;
  const int wave = tid >> 6;
  const float* xb = pcd + (size_t)b * NPTS * 3;

  const float cx = new_xyz[(size_t)bs * 3 + 0];
  const float cy = new_xyz[(size_t)bs * 3 + 1];
  const float cz = new_xyz[(size_t)bs * 3 + 2];

  for (int c = tid; c < 320; c += 256) feat[c] = 0.0f;

  // ---- ball query: wave w handles scale w ----
  if (wave < 3) {
    const int ns  = (wave == 0) ? 16 : (wave == 1) ? 32 : 128;
    const int off = (wave == 0) ? 0  : (wave == 1) ? 16 : 48;
    const float r2 = (wave == 0) ? (float)(0.1 * 0.1)
                   : (wave == 1) ? (float)(0.2 * 0.2)
                                 : (float)(0.4 * 0.4);
    int cnt = 0;
    for (int ch = 0; ch < NPTS / 64 && cnt < ns; ++ch) {
      int i = ch * 64 + lane;
      float dx = __fsub_rn(cx, xb[i * 3 + 0]);
      float dy = __fsub_rn(cy, xb[i * 3 + 1]);
      float dz = __fsub_rn(cz, xb[i * 3 + 2]);
      float sq = __fadd_rn(__fadd_rn(__fmul_rn(dx, dx), __fmul_rn(dy, dy)),
                           __fmul_rn(dz, dz));
      bool isin = sq < r2;
      unsigned long long mk = __ballot(isin);
      int pos = cnt + (int)__popcll(mk & ((1ull << lane) - 1ull));
      if (isin && pos < ns) lists[off + pos] = i;
      cnt += (int)__popcll(mk);
    }
    if (cnt > ns) cnt = ns;
    int first = lists[off];               // valid: center always in-radius
    for (int k = cnt + lane; k < ns; k += 64) lists[off + k] = first;
  }
  __syncthreads();

  // ---- scale 0: ns=16, 3->32->32->64 -> feat[0:64) ----
  {
    if (tid < 16) {
      int j = lists[0 + tid];
      hA[0 * 16 + tid] = __fsub_rn(xb[j * 3 + 0], cx);
      hA[1 * 16 + tid] = __fsub_rn(xb[j * 3 + 1], cy);
      hA[2 * 16 + tid] = __fsub_rn(xb[j * 3 + 2], cz);
    }
    __syncthreads();
    layer<3, 32, 16, false>(w00, b00, hA, hB, tid);  __syncthreads();
    layer<32, 32, 16, false>(w01, b01, hB, hA, tid); __syncthreads();
    layer<32, 64, 16, true>(w02, b02, hA, feat + 0, tid); __syncthreads();
  }
  // ---- scale 1: ns=32, 3->64->64->128 -> feat[64:192) ----
  {
    if (tid < 32) {
      int j = lists[16 + tid];
      hA[0 * 32 + tid] = __fsub_rn(xb[j * 3 + 0], cx);
      hA[1 * 32 + tid] = __fsub_rn(xb[j * 3 + 1], cy);
      hA[2 * 32 + tid] = __fsub_rn(xb[j * 3 + 2], cz);
    }
    __syncthreads();
    layer<3, 64, 32, false>(w10, b10, hA, hB, tid);  __syncthreads();
    layer<64, 64, 32, false>(w11, b11, hB, hA, tid); __syncthreads();
    layer<64, 128, 32, true>(w12, b12, hA, feat + 64, tid); __syncthreads();
  }
  // ---- scale 2: ns=128 in 2 tiles of 64, 3->64->96->128 -> feat[192:320) ----
  for (int tile = 0; tile < 2; ++tile) {
    if (tid < 64) {
      int j = lists[48 + tile * 64 + tid];
      hA[0 * 64 + tid] = __fsub_rn(xb[j * 3 + 0], cx);
      hA[1 * 64 + tid] = __fsub_rn(xb[j * 3 + 1], cy);
      hA[2 * 64 + tid] = __fsub_rn(xb[j * 3 + 2], cz);
    }
    __syncthreads();
    layer<3, 64, 64, false>(w20, b20, hA, hB, tid);  __syncthreads();
    layer<64, 96, 64, false>(w21, b21, hB, hA, tid); __syncthreads();
    layer<96, 128, 64, true>(w22, b22, hA, feat + 192, tid); __syncthreads();
  }

  // ---- final linear 320 -> 1 ----
  if (tid < 64) {
    float s = 0.0f;
#pragma unroll
    for (int c = 0; c < 5; ++c) s += feat[tid + c * 64] * wf[tid + c * 64];
#pragma unroll
    for (int o = 32; o > 0; o >>= 1) s += __shfl_down(s, o);
    if (tid == 0) out[bs] = s + bf[0];
  }
}

extern "C" void kernel_launch(void* const* d_in, const int* in_sizes, int n_in,
                              void* d_out, int out_size, void* d_ws, size_t ws_size,
                              hipStream_t stream) {
  const float* pcd = (const float*)d_in[0];
  float* new_xyz = (float*)d_ws;  // BATCH*NSAMP*3 floats = 48 KB

  fps_kernel<<<BATCH, 256, 0, stream>>>(pcd, new_xyz);

  msg_kernel<<<BATCH * NSAMP, 256, 0, stream>>>(
      pcd, new_xyz,
      (const float*)d_in[1],  (const float*)d_in[2],
      (const float*)d_in[3],  (const float*)d_in[4],
      (const float*)d_in[5],  (const float*)d_in[6],
      (const float*)d_in[7],  (const float*)d_in[8],
      (const float*)d_in[9],  (const float*)d_in[10],
      (const float*)d_in[11], (const float*)d_in[12],
      (const float*)d_in[13], (const float*)d_in[14],
      (const float*)d_in[15], (const float*)d_in[16],
      (const float*)d_in[17], (const float*)d_in[18],
      (const float*)d_in[19], (const float*)d_in[20],
      (float*)d_out);
}

// Round 3
// 818.741 us; speedup vs baseline: 1.3041x; 1.3041x over previous
//
#include <hip/hip_runtime.h>

#define BATCH 8
#define NPTS 4096
#define NSAMP 512   // npoint = NPTS/8

#define ROW_SHR(n) (0x110 | (n))
#define ROW_BCAST15 0x142
#define ROW_BCAST31 0x143

// one max-combine step on a packed u64 key via DPP (VALU latency, no LDS).
// CTRL/RMASK are template params: __builtin_amdgcn_update_dpp needs ICEs.
template <int CTRL, int RMASK>
__device__ __forceinline__ unsigned long long kmax_dpp(unsigned long long k) {
  unsigned lo = (unsigned)__builtin_amdgcn_update_dpp(0, (int)(unsigned)k,
                                                      CTRL, RMASK, 0xf, true);
  unsigned hi = (unsigned)__builtin_amdgcn_update_dpp(0, (int)(unsigned)(k >> 32),
                                                      CTRL, RMASK, 0xf, true);
  unsigned long long o = ((unsigned long long)hi << 32) | lo;
  return o > k ? o : k;   // masked/OOB lanes deliver 0 -> identity
}

// ---------------------------------------------------------------------------
// Kernel A: farthest point sampling. One block per batch, 256 threads.
// Exact fp32 (no FMA) so the argmax selection matches numpy bit-for-bit.
// Packed-key argmax: key = (float_bits(val) << 32) | ~idx  (val >= 0), so
// u64-max == (max val, tie -> smaller idx) == np.argmax first-occurrence.
// ---------------------------------------------------------------------------
__global__ __launch_bounds__(256) void fps_kernel(const float* __restrict__ pcd,
                                                  float* __restrict__ new_xyz) {
  __shared__ float4 s_pts[NPTS];                       // 64 KB
  __shared__ unsigned long long red[2][4];             // parity double-buffer

  const int b = blockIdx.x;
  const int t = threadIdx.x;
  const int wave = t >> 6;
  const int lane = t & 63;
  const float* xb = pcd + (size_t)b * NPTS * 3;

  float X[16], Y[16], Z[16], mind[16];
#pragma unroll
  for (int j = 0; j < 16; ++j) {
    int i = t + 256 * j;
    float x = xb[i * 3 + 0], y = xb[i * 3 + 1], z = xb[i * 3 + 2];
    X[j] = x; Y[j] = y; Z[j] = z;
    s_pts[i] = make_float4(x, y, z, 0.0f);
    mind[j] = 10000000000.0f;
  }
  __syncthreads();

  float px = xb[0], py = xb[1], pz = xb[2];            // idx 0 is first sample

  for (int it = 0; it < NSAMP; ++it) {
    if (t == 0) {
      size_t o = ((size_t)b * NSAMP + it) * 3;
      new_xyz[o + 0] = px; new_xyz[o + 1] = py; new_xyz[o + 2] = pz;
    }
    // ---- per-thread update + local argmax (exact fp32, first-occurrence) --
    float bv = -1.0f; int bi = 0;
#pragma unroll
    for (int j = 0; j < 16; ++j) {
      float dx = __fsub_rn(X[j], px);
      float dy = __fsub_rn(Y[j], py);
      float dz = __fsub_rn(Z[j], pz);
      float d = __fadd_rn(__fadd_rn(__fmul_rn(dx, dx), __fmul_rn(dy, dy)),
                          __fmul_rn(dz, dz));
      float m = fminf(mind[j], d);
      mind[j] = m;
      if (m > bv) { bv = m; bi = t + 256 * j; }        // strict >: first occ.
    }
    // ---- pack and wave-reduce via DPP (lane 63 ends with wave max) --------
    unsigned long long key =
        ((unsigned long long)__float_as_uint(bv) << 32) |
        (unsigned long long)(~(unsigned)bi);
    key = kmax_dpp<ROW_SHR(1), 0xf>(key);
    key = kmax_dpp<ROW_SHR(2), 0xf>(key);
    key = kmax_dpp<ROW_SHR(4), 0xf>(key);
    key = kmax_dpp<ROW_SHR(8), 0xf>(key);
    key = kmax_dpp<ROW_BCAST15, 0xa>(key);
    key = kmax_dpp<ROW_BCAST31, 0xc>(key);
    unsigned wlo = (unsigned)__builtin_amdgcn_readlane((int)(unsigned)key, 63);
    unsigned whi = (unsigned)__builtin_amdgcn_readlane((int)(unsigned)(key >> 32), 63);
    if (lane == 0)
      red[it & 1][wave] = ((unsigned long long)whi << 32) | wlo;
    __syncthreads();
    // ---- every thread redundantly combines the 4 wave winners -------------
    unsigned long long g = red[it & 1][0];
    unsigned long long g1 = red[it & 1][1];
    unsigned long long g2 = red[it & 1][2];
    unsigned long long g3 = red[it & 1][3];
    if (g1 > g) g = g1;
    if (g2 > g) g = g2;
    if (g3 > g) g = g3;
    int nxt = (int)(~(unsigned)g);
    float4 p = s_pts[nxt];
    px = p.x; py = p.y; pz = p.z;
  }
}

// ---------------------------------------------------------------------------
// Tiled MLP layer: block = 16 n-threads x 16 oc-threads.
// h stored channel-major in LDS: h[c][n] with row stride NT.
// Weights read straight from global (L2-resident, lanes dedup/broadcast).
// FINAL: fuse bias+relu+max-over-n via LDS integer atomicMax (values >= 0).
// ---------------------------------------------------------------------------
template <int CIN, int COUT, int NT, bool FINAL>
__device__ __forceinline__ void layer(const float* __restrict__ w,
                                      const float* __restrict__ bias,
                                      const float* hin, float* hout, int tid) {
  constexpr int TN = NT / 16;
  constexpr int TOC = COUT / 16;
  const int tn = tid & 15, toc = tid >> 4;
  float acc[TOC][TN];
#pragma unroll
  for (int j = 0; j < TOC; ++j) {
    float bj = bias[toc * TOC + j];
#pragma unroll
    for (int i = 0; i < TN; ++i) acc[j][i] = bj;
  }
#pragma unroll 4
  for (int ic = 0; ic < CIN; ++ic) {
    float hv[TN];
#pragma unroll
    for (int i = 0; i < TN; ++i) hv[i] = hin[ic * NT + tn * TN + i];
    float wv[TOC];
#pragma unroll
    for (int j = 0; j < TOC; ++j) wv[j] = w[ic * COUT + toc * TOC + j];
#pragma unroll
    for (int j = 0; j < TOC; ++j)
#pragma unroll
      for (int i = 0; i < TN; ++i) acc[j][i] = fmaf(hv[i], wv[j], acc[j][i]);
  }
  if (FINAL) {
#pragma unroll
    for (int j = 0; j < TOC; ++j) {
      float m = 0.0f;  // relu floor
#pragma unroll
      for (int i = 0; i < TN; ++i) m = fmaxf(m, acc[j][i]);
      atomicMax((int*)&hout[toc * TOC + j], __float_as_int(m));
    }
  } else {
#pragma unroll
    for (int j = 0; j < TOC; ++j)
#pragma unroll
      for (int i = 0; i < TN; ++i)
        hout[(toc * TOC + j) * NT + tn * TN + i] = fmaxf(acc[j][i], 0.0f);
  }
}

// ---------------------------------------------------------------------------
// Kernel B: one block per (b, s) sample point. Ball query (3 scales, waves
// 0..2, ballot-prefix ordered append, exact fp32) then per-scale MLP + max,
// then fused final 320->1 linear.
// ---------------------------------------------------------------------------
__global__ __launch_bounds__(256) void msg_kernel(
    const float* __restrict__ pcd, const float* __restrict__ new_xyz,
    const float* __restrict__ w00, const float* __restrict__ b00,
    const float* __restrict__ w01, const float* __restrict__ b01,
    const float* __restrict__ w02, const float* __restrict__ b02,
    const float* __restrict__ w10, const float* __restrict__ b10,
    const float* __restrict__ w11, const float* __restrict__ b11,
    const float* __restrict__ w12, const float* __restrict__ b12,
    const float* __restrict__ w20, const float* __restrict__ b20,
    const float* __restrict__ w21, const float* __restrict__ b21,
    const float* __restrict__ w22, const float* __restrict__ b22,
    const float* __restrict__ wf, const float* __restrict__ bf,
    float* __restrict__ out) {
  __shared__ float hA[96 * 64];
  __shared__ float hB[64 * 64];
  __shared__ int   lists[176];   // 16 + 32 + 128
  __shared__ float feat[320];

  const int bs = blockIdx.x;
  const int b = bs >> 9;
  const int tid = threadIdx.x;
  const int lane = tid & 63;
  const int wave = tid >> 6;
  const float* xb = pcd + (size_t)b * NPTS * 3;

  const float cx = new_xyz[(size_t)bs * 3 + 0];
  const float cy = new_xyz[(size_t)bs * 3 + 1];
  const float cz = new_xyz[(size_t)bs * 3 + 2];

  for (int c = tid; c < 320; c += 256) feat[c] = 0.0f;

  // ---- ball query: wave w handles scale w ----
  if (wave < 3) {
    const int ns  = (wave == 0) ? 16 : (wave == 1) ? 32 : 128;
    const int off = (wave == 0) ? 0  : (wave == 1) ? 16 : 48;
    const float r2 = (wave == 0) ? (float)(0.1 * 0.1)
                   : (wave == 1) ? (float)(0.2 * 0.2)
                                 : (float)(0.4 * 0.4);
    int cnt = 0;
    for (int ch = 0; ch < NPTS / 64 && cnt < ns; ++ch) {
      int i = ch * 64 + lane;
      float dx = __fsub_rn(cx, xb[i * 3 + 0]);
      float dy = __fsub_rn(cy, xb[i * 3 + 1]);
      float dz = __fsub_rn(cz, xb[i * 3 + 2]);
      float sq = __fadd_rn(__fadd_rn(__fmul_rn(dx, dx), __fmul_rn(dy, dy)),
                           __fmul_rn(dz, dz));
      bool isin = sq < r2;
      unsigned long long mk = __ballot(isin);
      int pos = cnt + (int)__popcll(mk & ((1ull << lane) - 1ull));
      if (isin && pos < ns) lists[off + pos] = i;
      cnt += (int)__popcll(mk);
    }
    if (cnt > ns) cnt = ns;
    int first = lists[off];               // valid: center always in-radius
    for (int k = cnt + lane; k < ns; k += 64) lists[off + k] = first;
  }
  __syncthreads();

  // ---- scale 0: ns=16, 3->32->32->64 -> feat[0:64) ----
  {
    if (tid < 16) {
      int j = lists[0 + tid];
      hA[0 * 16 + tid] = __fsub_rn(xb[j * 3 + 0], cx);
      hA[1 * 16 + tid] = __fsub_rn(xb[j * 3 + 1], cy);
      hA[2 * 16 + tid] = __fsub_rn(xb[j * 3 + 2], cz);
    }
    __syncthreads();
    layer<3, 32, 16, false>(w00, b00, hA, hB, tid);  __syncthreads();
    layer<32, 32, 16, false>(w01, b01, hB, hA, tid); __syncthreads();
    layer<32, 64, 16, true>(w02, b02, hA, feat + 0, tid); __syncthreads();
  }
  // ---- scale 1: ns=32, 3->64->64->128 -> feat[64:192) ----
  {
    if (tid < 32) {
      int j = lists[16 + tid];
      hA[0 * 32 + tid] = __fsub_rn(xb[j * 3 + 0], cx);
      hA[1 * 32 + tid] = __fsub_rn(xb[j * 3 + 1], cy);
      hA[2 * 32 + tid] = __fsub_rn(xb[j * 3 + 2], cz);
    }
    __syncthreads();
    layer<3, 64, 32, false>(w10, b10, hA, hB, tid);  __syncthreads();
    layer<64, 64, 32, false>(w11, b11, hB, hA, tid); __syncthreads();
    layer<64, 128, 32, true>(w12, b12, hA, feat + 64, tid); __syncthreads();
  }
  // ---- scale 2: ns=128 in 2 tiles of 64, 3->64->96->128 -> feat[192:320) ----
  for (int tile = 0; tile < 2; ++tile) {
    if (tid < 64) {
      int j = lists[48 + tile * 64 + tid];
      hA[0 * 64 + tid] = __fsub_rn(xb[j * 3 + 0], cx);
      hA[1 * 64 + tid] = __fsub_rn(xb[j * 3 + 1], cy);
      hA[2 * 64 + tid] = __fsub_rn(xb[j * 3 + 2], cz);
    }
    __syncthreads();
    layer<3, 64, 64, false>(w20, b20, hA, hB, tid);  __syncthreads();
    layer<64, 96, 64, false>(w21, b21, hB, hA, tid); __syncthreads();
    layer<96, 128, 64, true>(w22, b22, hA, feat + 192, tid); __syncthreads();
  }

  // ---- final linear 320 -> 1 ----
  if (tid < 64) {
    float s = 0.0f;
#pragma unroll
    for (int c = 0; c < 5; ++c) s += feat[tid + c * 64] * wf[tid + c * 64];
#pragma unroll
    for (int o = 32; o > 0; o >>= 1) s += __shfl_down(s, o);
    if (tid == 0) out[bs] = s + bf[0];
  }
}

extern "C" void kernel_launch(void* const* d_in, const int* in_sizes, int n_in,
                              void* d_out, int out_size, void* d_ws, size_t ws_size,
                              hipStream_t stream) {
  const float* pcd = (const float*)d_in[0];
  float* new_xyz = (float*)d_ws;  // BATCH*NSAMP*3 floats = 48 KB

  fps_kernel<<<BATCH, 256, 0, stream>>>(pcd, new_xyz);

  msg_kernel<<<BATCH * NSAMP, 256, 0, stream>>>(
      pcd, new_xyz,
      (const float*)d_in[1],  (const float*)d_in[2],
      (const float*)d_in[3],  (const float*)d_in[4],
      (const float*)d_in[5],  (const float*)d_in[6],
      (const float*)d_in[7],  (const float*)d_in[8],
      (const float*)d_in[9],  (const float*)d_in[10],
      (const float*)d_in[11], (const float*)d_in[12],
      (const float*)d_in[13], (const float*)d_in[14],
      (const float*)d_in[15], (const float*)d_in[16],
      (const float*)d_in[17], (const float*)d_in[18],
      (const float*)d_in[19], (const float*)d_in[20],
      (float*)d_out);
}